// Round 19
// baseline (1260.890 us; speedup 1.0000x reference)
//
#include <hip/hip_runtime.h>
#include <hip/hip_bf16.h>
#include <math.h>

#define PI_F 3.14159265358979323846f

typedef __attribute__((ext_vector_type(8))) short s8v;
typedef __attribute__((ext_vector_type(4))) short s4v;
typedef __attribute__((ext_vector_type(4))) float f4v;

#define MFMA16(a, b, c) __builtin_amdgcn_mfma_f32_16x16x32_bf16(a, b, c, 0, 0, 0)

// fast erf, A&S 7.1.26, |err| <= ~1e-6 (rcp adds ~1ulp)
__device__ __forceinline__ float erf_f(float x) {
    float a = fabsf(x);
    float t = __builtin_amdgcn_rcpf(fmaf(0.3275911f, a, 1.0f));
    float p = t * fmaf(t, fmaf(t, fmaf(t, fmaf(t, 1.061405429f, -1.453152027f),
                1.421413741f), -0.284496736f), 0.254829592f);
    float r = 1.0f - p * __expf(-a * a);
    return copysignf(r, x);
}
__device__ __forceinline__ float gelu_f(float x) {
    return 0.5f * x * (1.0f + erf_f(x * 0.70710678118654752440f));
}

// split x = hi + lo, both bf16, via native HW converts (RNE). lo corrects hi
// exactly; total rel err ~2^-17.
__device__ __forceinline__ void split_bf16(float x, unsigned short& h, unsigned short& l) {
    __hip_bfloat16 hb = __float2bfloat16(x);
    float hf = __bfloat162float(hb);
    __hip_bfloat16 lb = __float2bfloat16(x - hf);
    h = __builtin_bit_cast(unsigned short, hb);
    l = __builtin_bit_cast(unsigned short, lb);
}

// pack 8 fp32 into swizzled hi/lo LDS B-buffer (32KB: hi @0, lo @16384)
__device__ __forceinline__ void pack_write8(char* Bb, int px, int k0, const float* v) {
    s8v hv, lv;
    #pragma unroll
    for (int j = 0; j < 8; ++j) {
        unsigned short h, l;
        split_bf16(v[j], h, l);
        hv[j] = (short)h; lv[j] = (short)l;
    }
    int byt = px * 256 + ((k0 * 2) ^ ((px & 15) << 4));
    *(s8v*)(Bb + byt) = hv;
    *(s8v*)(Bb + 16384 + byt) = lv;
}

// hi-only pack (16KB buffer): single RNE convert per value
__device__ __forceinline__ void pack_write8_h(char* Bb, int px, int k0, const float* v) {
    s8v hv;
    #pragma unroll
    for (int j = 0; j < 8; ++j) {
        __hip_bfloat16 hb = __float2bfloat16(v[j]);
        hv[j] = (short)__builtin_bit_cast(unsigned short, hb);
    }
    int byt = px * 256 + ((k0 * 2) ^ ((px & 15) << 4));
    *(s8v*)(Bb + byt) = hv;
}

// 3-term split GEMM (A split, B split; 32KB buffer). Used by k_proj only.
template<int KC0, int KCN>
__device__ __forceinline__ void gemm_range(const char* Bb, const unsigned short* wp,
                                           int lane, int wv, f4v acc[2][4]) {
    #pragma unroll
    for (int kc = KC0; kc < KC0 + KCN; ++kc) {
        s8v bh[4], bl[4];
        int k0 = kc * 32 + ((lane >> 4) << 3);
        #pragma unroll
        for (int pt = 0; pt < 4; ++pt) {
            int px = pt * 16 + (lane & 15);
            int byt = px * 256 + ((k0 * 2) ^ ((px & 15) << 4));
            bh[pt] = *(const s8v*)(Bb + byt);
            bl[pt] = *(const s8v*)(Bb + 16384 + byt);
        }
        #pragma unroll
        for (int oi = 0; oi < 2; ++oi) {
            const unsigned short* ap = wp + (wv * 2 + oi) * 2048 + kc * 512 + lane * 8;
            s8v ah = *(const s8v*)ap;
            s8v al = *(const s8v*)(ap + 16384);
            #pragma unroll
            for (int pt = 0; pt < 4; ++pt) {
                acc[oi][pt] = MFMA16(ah, bh[pt], acc[oi][pt]);
                acc[oi][pt] = MFMA16(ah, bl[pt], acc[oi][pt]);
                acc[oi][pt] = MFMA16(al, bh[pt], acc[oi][pt]);
            }
        }
    }
}

// 2-term (B hi-only; A full split). All k_layer GEMMs use this.
template<int KC0, int KCN>
__device__ __forceinline__ void gemm_range_bh(const char* Bb, const unsigned short* wp,
                                              int lane, int wv, f4v acc[2][4]) {
    #pragma unroll
    for (int kc = KC0; kc < KC0 + KCN; ++kc) {
        s8v bh[4];
        int k0 = kc * 32 + ((lane >> 4) << 3);
        #pragma unroll
        for (int pt = 0; pt < 4; ++pt) {
            int px = pt * 16 + (lane & 15);
            int byt = px * 256 + ((k0 * 2) ^ ((px & 15) << 4));
            bh[pt] = *(const s8v*)(Bb + byt);
        }
        #pragma unroll
        for (int oi = 0; oi < 2; ++oi) {
            const unsigned short* ap = wp + (wv * 2 + oi) * 2048 + kc * 512 + lane * 8;
            s8v ah = *(const s8v*)ap;
            s8v al = *(const s8v*)(ap + 16384);
            #pragma unroll
            for (int pt = 0; pt < 4; ++pt) {
                acc[oi][pt] = MFMA16(ah, bh[pt], acc[oi][pt]);
                acc[oi][pt] = MFMA16(al, bh[pt], acc[oi][pt]);
            }
        }
    }
}

// ---------------- weight pre-split+pack: 13 fp32 128x128 mats ----------------
__global__ __launch_bounds__(256) void k_pack_w(const float* __restrict__ mlp1w,
        const float* __restrict__ mlp2w, const float* __restrict__ wsw,
        const float* __restrict__ fc1aw, unsigned short* __restrict__ wpack) {
    int idx = blockIdx.x * 256 + threadIdx.x;
    if (idx >= 212992) return;           // 13 * 16384
    int mat = idx >> 14, e = idx & 16383;
    const float* src = mat < 4  ? mlp1w + mat * 16384 + e
                     : mat < 8  ? mlp2w + (mat - 4) * 16384 + e
                     : mat < 12 ? wsw + (mat - 8) * 16384 + e
                                : fc1aw + e;
    float x = *src;
    unsigned short h, l;
    split_bf16(x, h, l);
    int o = e >> 7, i = e & 127;
    int pos = (o >> 4) * 2048 + (i >> 5) * 512 + (((i >> 3) & 3) * 16 + (o & 15)) * 8 + (i & 7);
    wpack[(size_t)mat * 32768 + pos] = h;
    wpack[(size_t)mat * 32768 + 16384 + pos] = l;
}

// ---------------- twiddle fragment tables ----------------
__global__ void k_pack_ef(unsigned short* __restrict__ efp,
                          unsigned short* __restrict__ ef2,
                          unsigned short* __restrict__ ef3) {
    int t = blockIdx.x * 256 + threadIdx.x;
    if (t < 4096) {
        int j = t & 7, lane = (t >> 3) & 63, nt = (t >> 9) & 1, kc = t >> 10;
        int w = kc * 32 + ((lane >> 4) << 3) + j;
        int q = nt * 16 + (lane & 15);
        int ky = q >> 1, c = q & 1;
        int m = (ky * w) & 127;
        float th = (2.0f * PI_F / 128.0f) * (float)m;
        float v = c ? -sinf(th) : cosf(th);
        unsigned short h, l;
        split_bf16(v, h, l);
        efp[t] = h;
        efp[4096 + t] = l;
    }
    if (t < 4096) {
        int j = t & 7, lane = (t >> 3) & 63, wt = t >> 9;
        int w = wt * 16 + (lane & 15);
        int q = ((lane >> 4) << 3) + j;
        int ky = q >> 1, c = q & 1;
        float g = (ky == 0 ? 1.0f : 2.0f) * (1.0f / 16384.0f);
        int m = (ky * w) & 127;
        float th = (2.0f * PI_F / 128.0f) * (float)m;
        float v = (c ? -sinf(th) : cosf(th)) * g;
        unsigned short h, l;
        split_bf16(v, h, l);
        ef2[t] = h;
        ef2[4096 + t] = l;
    }
    if (t < 16384) {
        int j = t & 7, lane = (t >> 3) & 63, kt = (t >> 9) & 7, ct = t >> 12;
        int k = kt * 32 + ((lane >> 4) << 3) + j;
        int col = ct * 16 + (lane & 15);
        int h = k >> 1, cb = k & 1;
        int kxi = col >> 1, cp = col & 1;
        int f = kxi < 16 ? kxi : kxi - 32;
        int m = ((f * h) % 128 + 128) & 127;
        float th = (2.0f * PI_F / 128.0f) * (float)m;
        float Er = cosf(th), Ei = -sinf(th);
        float v = (cb == 0) ? (cp == 0 ? Er : Ei) : (cp == 0 ? -Ei : Er);
        unsigned short hh, ll;
        split_bf16(v, hh, ll);
        ef3[t] = hh;
        ef3[16384 + t] = ll;
    }
}

// ---------------- tabH for inverse h-DFT ----------------
__global__ void k_init_tables(float* __restrict__ tabH) {
    int idx = blockIdx.x * 256 + threadIdx.x;
    if (idx < 8192) {
        int c = idx & 1, kxi = (idx >> 1) & 31, h = idx >> 6;
        int f = kxi < 16 ? kxi : kxi - 32;
        int m = ((f * h) % 128 + 128) & 127;
        float th = (2.0f * PI_F / 128.0f) * (float)m;
        tabH[idx] = c ? -sinf(th) : cosf(th);
    }
}

// ---------------- lifting (4 px / thread, float4) ----------------
__global__ __launch_bounds__(256) void k_lift(const float* __restrict__ xin,
        const float* __restrict__ w0, const float* __restrict__ b0,
        float* __restrict__ xout) {
    int idx = blockIdx.x * 256 + threadIdx.x;     // 8,388,608 quads
    int wq = idx & 31, h = (idx >> 5) & 127, c = (idx >> 12) & 127, b = idx >> 19;
    const float4* xp = (const float4*)(xin + ((size_t)(b * 128 + h) * 128 + wq * 4) * 2);
    float4 p01 = xp[0], p23 = xp[1];
    float wa = w0[c], wbv = w0[128 + c], wg = w0[256 + c], wd = w0[384 + c];
    float base = (float)h * (1.0f / 127.0f) * wg + b0[c];
    float ws = (1.0f / 127.0f) * wd;
    float4 v;
    v.x = p01.x * wa + p01.y * wbv + (float)(wq * 4 + 0) * ws + base;
    v.y = p01.z * wa + p01.w * wbv + (float)(wq * 4 + 1) * ws + base;
    v.z = p23.x * wa + p23.y * wbv + (float)(wq * 4 + 2) * ws + base;
    v.w = p23.z * wa + p23.w * wbv + (float)(wq * 4 + 3) * ws + base;
    *(float4*)(xout + ((size_t)(b * 128 + c) * 128 + h) * 128 + wq * 4) = v;
}

// ---------------- fused forward transform: x(b,c) -> F[bi][kxi*16+ky]cplx ------
__global__ __launch_bounds__(256) void k_fwd(const float* __restrict__ x,
        float* __restrict__ F, const unsigned short* __restrict__ efp,
        const unsigned short* __restrict__ ef3) {
    __shared__ __align__(16) char Xb[32768];
    __shared__ __align__(16) char Tq[16384];
    int t = threadIdx.x;
    int bi = blockIdx.x;
    int lane = t & 63, wv = t >> 6;
    const float4* xg = (const float4*)(x + (size_t)bi * 16384);

    for (int half = 0; half < 2; ++half) {
        __syncthreads();
        #pragma unroll
        for (int k = 0; k < 8; ++k) {
            int idx4 = k * 256 + t;
            float4 f = xg[half * 2048 + idx4];
            int row = idx4 >> 5;
            int w0 = (idx4 & 31) * 4;
            s4v h4, l4;
            const float* fp = (const float*)&f;
            #pragma unroll
            for (int q = 0; q < 4; ++q) {
                unsigned short hh, ll;
                split_bf16(fp[q], hh, ll);
                h4[q] = (short)hh; l4[q] = (short)ll;
            }
            int byt = row * 256 + ((w0 * 2) ^ ((row & 15) << 4));
            *(s4v*)(Xb + byt) = h4;
            *(s4v*)(Xb + 16384 + byt) = l4;
        }
        __syncthreads();
        f4v acc[2];
        acc[0] = (f4v){0.f, 0.f, 0.f, 0.f};
        acc[1] = (f4v){0.f, 0.f, 0.f, 0.f};
        #pragma unroll
        for (int kc = 0; kc < 4; ++kc) {
            int row = wv * 16 + (lane & 15);
            int k0 = kc * 32 + ((lane >> 4) << 3);
            int byt = row * 256 + ((k0 * 2) ^ ((row & 15) << 4));
            s8v ah = *(const s8v*)(Xb + byt);
            s8v al = *(const s8v*)(Xb + 16384 + byt);
            #pragma unroll
            for (int nt = 0; nt < 2; ++nt) {
                const unsigned short* bp = efp + ((kc * 2 + nt) * 64 + lane) * 8;
                s8v bh = *(const s8v*)bp;
                s8v bl = *(const s8v*)(bp + 4096);
                acc[nt] = MFMA16(ah, bh, acc[nt]);
                acc[nt] = MFMA16(ah, bl, acc[nt]);
                acc[nt] = MFMA16(al, bh, acc[nt]);
            }
        }
        // scatter T (split-bf16) into Tq: T[h][q] -> Tq[ky=q>>1][k=2h+(q&1)]
        #pragma unroll
        for (int nt = 0; nt < 2; ++nt) {
            int q = nt * 16 + (lane & 15);
            int ky = q >> 1, c = q & 1;
            #pragma unroll
            for (int r = 0; r < 4; ++r) {
                int h = half * 64 + wv * 16 + ((lane >> 4) << 2) + r;
                unsigned short hh, ll;
                split_bf16(acc[nt][r], hh, ll);
                int byt = ky * 512 + ((4 * h + 2 * c) ^ ((ky & 15) << 4));
                *(unsigned short*)(Tq + byt) = hh;
                *(unsigned short*)(Tq + 8192 + byt) = ll;
            }
        }
    }
    __syncthreads();
    f4v fa = (f4v){0.f, 0.f, 0.f, 0.f};
    #pragma unroll
    for (int kt = 0; kt < 8; ++kt) {
        int ky = lane & 15;
        int byt = ky * 512 + ((kt * 64 + ((lane >> 4) << 4)) ^ ((ky & 15) << 4));
        s8v ah = *(const s8v*)(Tq + byt);
        s8v al = *(const s8v*)(Tq + 8192 + byt);
        const unsigned short* bp = ef3 + ((wv * 8 + kt) * 64 + lane) * 8;
        s8v bh = *(const s8v*)bp;
        s8v bl = *(const s8v*)(bp + 16384);
        fa = MFMA16(ah, bh, fa);
        fa = MFMA16(ah, bl, fa);
        fa = MFMA16(al, bh, fa);
    }
    int col = wv * 16 + (lane & 15);
    int kxi = col >> 1, cp = col & 1;
    float* Fb = F + (size_t)bi * 1024 + kxi * 32 + cp;
    #pragma unroll
    for (int r = 0; r < 4; ++r) {
        int ky = ((lane >> 4) << 2) + r;
        Fb[ky * 2] = fa[r];
    }
}

// ---------------- modemix v3 (tier 2): F staged through LDS (32KB), 2 stages ----
__global__ __launch_bounds__(256, 4) void k_modemix2(const float* __restrict__ F,
        float* __restrict__ G0, float* __restrict__ G1,
        float* __restrict__ G2, float* __restrict__ G3,
        const float* __restrict__ w1r, const float* __restrict__ w1i,
        const float* __restrict__ w2r, const float* __restrict__ w2i) {
    __shared__ __align__(16) float2 Fs[4096];    // [b 4][i 16][m 64], 32 KB
    int t = threadIdx.x;
    int m = blockIdx.x * 64 + (t & 63);
    int o = blockIdx.y * 4 + (t >> 6);
    int bz = blockIdx.z;
    int iq = bz >> 2;
    int bq = bz & 3;
    const size_t i0 = (size_t)iq * 32;
    int b0 = bq * 4;
    const float* wrp = (m < 256) ? w1r : w2r;
    const float* wip = (m < 256) ? w1i : w2i;
    int ms = m & 255;
    float accr[4], acci[4];
    #pragma unroll
    for (int b = 0; b < 4; ++b) { accr[b] = 0.f; acci[b] = 0.f; }
    const float* wrb = wrp + (i0 * 128 + o) * 256 + ms;
    const float* wib = wip + (i0 * 128 + o) * 256 + ms;
    int m0 = blockIdx.x * 64;
    const float2* F2 = (const float2*)F;

    for (int ih = 0; ih < 2; ++ih) {
        __syncthreads();                         // protect Fs reuse
        #pragma unroll
        for (int k = 0; k < 16; ++k) {
            int idx = k * 256 + t;               // m=idx&63, i=(idx>>6)&15, b=idx>>10
            int fm = idx & 63, fi = (idx >> 6) & 15, fb = idx >> 10;
            Fs[idx] = F2[(size_t)(b0 + fb) * 65536 + (i0 + ih * 16 + fi) * 512 + m0 + fm];
        }
        __syncthreads();
        int ml = t & 63;
        #pragma unroll 4
        for (int ii = 0; ii < 16; ++ii) {
            size_t gi = (size_t)(ih * 16 + ii);
            float wr = wrb[gi * 32768];
            float wi = wib[gi * 32768];
            const float2* fp = Fs + ii * 64 + ml;
            #pragma unroll
            for (int b = 0; b < 4; ++b) {
                float2 f = fp[b * 1024];
                accr[b] += f.x * wr - f.y * wi;
                acci[b] += f.x * wi + f.y * wr;
            }
        }
    }
    float* Gsel = (iq == 0 ? G0 : iq == 1 ? G1 : iq == 2 ? G2 : G3);
    float2* Gp = (float2*)Gsel;
    #pragma unroll
    for (int b = 0; b < 4; ++b) {
        Gp[(size_t)(b0 + b) * 65536 + (size_t)o * 512 + m] = make_float2(accr[b], acci[b]);
    }
}

// ---------------- per-mode complex C x C mix, fallback tiers (0/1) ----------------
template<int TIER>
__global__ __launch_bounds__(256, 4) void k_modemix(const float* __restrict__ F,
        float* __restrict__ G0, float* __restrict__ G1,
        float* __restrict__ G2, float* __restrict__ G3,
        const float* __restrict__ w1r, const float* __restrict__ w1i,
        const float* __restrict__ w2r, const float* __restrict__ w2i) {
    int t = threadIdx.x;
    int m = blockIdx.x * 64 + (t & 63);
    int o = blockIdx.y * 4 + (t >> 6);
    int bz = blockIdx.z;
    int iq = (TIER == 0) ? 0 : (bz >> 2);
    int bq = (TIER == 0) ? bz : (bz & 3);
    const int ni = (TIER == 1) ? 64 : 128;
    const size_t i0 = (size_t)iq * ni;
    int b0 = bq * 4;
    const float* wrp = (m < 256) ? w1r : w2r;
    const float* wip = (m < 256) ? w1i : w2i;
    int ms = m & 255;
    float accr[4], acci[4];
    #pragma unroll
    for (int b = 0; b < 4; ++b) { accr[b] = 0.f; acci[b] = 0.f; }
    const float* wrb = wrp + (i0 * 128 + o) * 256 + ms;
    const float* wib = wip + (i0 * 128 + o) * 256 + ms;
    const float2* F2 = (const float2*)F + (size_t)b0 * 65536 + i0 * 512 + m;
    #pragma unroll 4
    for (int ii = 0; ii < ni; ++ii) {
        float wr = wrb[(size_t)ii * 32768];
        float wi = wib[(size_t)ii * 32768];
        const float2* Fp = F2 + (size_t)ii * 512;
        #pragma unroll
        for (int b = 0; b < 4; ++b) {
            float2 f = Fp[(size_t)b * 65536];
            accr[b] += f.x * wr - f.y * wi;
            acci[b] += f.x * wi + f.y * wr;
        }
    }
    float* Gsel = (TIER == 1) ? (iq ? G1 : G0) : G0;
    float2* Gp = (float2*)Gsel;
    #pragma unroll
    for (int b = 0; b < 4; ++b) {
        Gp[(size_t)(b0 + b) * 65536 + (size_t)o * 512 + m] = make_float2(accr[b], acci[b]);
    }
}

// ---------------- inverse DFT along h -> Z (bf16 hi/lo, h-major [b][h][c][q]) ----
template<int NADD>
__global__ __launch_bounds__(256) void k_idft_h(const float* __restrict__ G0,
        const float* __restrict__ G1, const float* __restrict__ G2,
        const float* __restrict__ G3, unsigned short* __restrict__ Zh,
        unsigned short* __restrict__ Zl, const float* __restrict__ tabH) {
    __shared__ float Gs[1024];
    __shared__ float Eh[8192];
    int t = threadIdx.x, bo = blockIdx.x;
    #pragma unroll
    for (int k = 0; k < 32; ++k) Eh[k * 256 + t] = tabH[k * 256 + t];
    size_t base = (size_t)bo * 1024;
    #pragma unroll
    for (int k = 0; k < 4; ++k) {
        size_t off = base + k * 256 + t;
        float v = G0[off];
        if (NADD > 1) v += G1[off];
        if (NADD > 2) { v += G2[off]; v += G3[off]; }
        Gs[k * 256 + t] = v;
    }
    __syncthreads();
    int ky = t & 15, hb = t >> 4;
    float zr[8], zi[8];
    #pragma unroll
    for (int j = 0; j < 8; ++j) { zr[j] = 0.f; zi[j] = 0.f; }
    for (int kxi = 0; kxi < 32; ++kxi) {
        float gr = Gs[(kxi * 16 + ky) * 2], gi = Gs[(kxi * 16 + ky) * 2 + 1];
        #pragma unroll
        for (int j = 0; j < 8; ++j) {
            int h = hb + 16 * j;
            float c = Eh[h * 64 + kxi * 2], s = Eh[h * 64 + kxi * 2 + 1];
            zr[j] += gr * c + gi * s;
            zi[j] += gi * c - gr * s;
        }
    }
    int b = bo >> 7, c = bo & 127;
    #pragma unroll
    for (int j = 0; j < 8; ++j) {
        int h = hb + 16 * j;
        size_t off = (((size_t)(b * 128 + h)) * 128 + c) * 32 + ky * 2;
        unsigned short hh, ll;
        split_bf16(zr[j], hh, ll);
        Zh[off] = hh; Zl[off] = ll;
        split_bf16(zi[j], hh, ll);
        Zh[off + 1] = hh; Zl[off + 1] = ll;
    }
}

// ---------------- fused layer tail: Z(split,h-major) -> S -> MLP + skip ----------
// All GEMMs B-hi-only -> Bb is 16KB -> 6 blocks/CU; (256,6): VGPR budget 85 >= 64.
template<int ACT>
__global__ __launch_bounds__(256, 6) void k_layer(
    const unsigned short* __restrict__ Zh, const unsigned short* __restrict__ Zl,
    const float* __restrict__ xin,
    const unsigned short* __restrict__ w1p, const float* __restrict__ b1,
    const unsigned short* __restrict__ w2p, const float* __restrict__ b2,
    const unsigned short* __restrict__ wskp, const float* __restrict__ bsk,
    const unsigned short* __restrict__ ef2, float* __restrict__ xout)
{
    __shared__ __align__(16) char Bb[16384];
    int t = threadIdx.x;
    int b = blockIdx.y;
    int p0 = blockIdx.x * 64;
    int h = p0 >> 7, w0 = p0 & 127;
    int lane = t & 63, wv = t >> 6;

    // ---- P0: S = Z . E2 via MFMA (K=32); Z coalesced; S stored bf16-HI-ONLY ----
    {
        int q0 = (lane >> 4) << 3;
        s8v zah[2], zal[2];
        #pragma unroll
        for (int ct = 0; ct < 2; ++ct) {
            int c = wv * 32 + ct * 16 + (lane & 15);
            size_t off = (((size_t)(b * 128 + h)) * 128 + c) * 32 + q0;
            zah[ct] = *(const s8v*)(Zh + off);
            zal[ct] = *(const s8v*)(Zl + off);
        }
        int wtg0 = w0 >> 4;
        #pragma unroll
        for (int wt = 0; wt < 4; ++wt) {
            const unsigned short* bp = ef2 + ((wtg0 + wt) * 64 + lane) * 8;
            s8v bh = *(const s8v*)bp;
            s8v bl = *(const s8v*)(bp + 4096);
            #pragma unroll
            for (int ct = 0; ct < 2; ++ct) {
                f4v c4 = (f4v){0.f, 0.f, 0.f, 0.f};
                c4 = MFMA16(zah[ct], bh, c4);
                c4 = MFMA16(zah[ct], bl, c4);
                c4 = MFMA16(zal[ct], bh, c4);
                int px = wt * 16 + (lane & 15);
                int c0 = wv * 32 + ct * 16 + ((lane >> 4) << 2);
                s4v h4;
                #pragma unroll
                for (int r = 0; r < 4; ++r) {
                    __hip_bfloat16 hb = __float2bfloat16(c4[r]);
                    h4[r] = (short)__builtin_bit_cast(unsigned short, hb);
                }
                int byt = px * 256 + ((c0 * 2) ^ ((px & 15) << 4));
                *(s4v*)(Bb + byt) = h4;
            }
        }
    }
    __syncthreads();

    f4v acc[2][4];
    #pragma unroll
    for (int oi = 0; oi < 2; ++oi)
        #pragma unroll
        for (int pt = 0; pt < 4; ++pt) acc[oi][pt] = (f4v){0.f, 0.f, 0.f, 0.f};

    // ---- P1: acc = W1 . S (B hi-only, 2-term) ----
    gemm_range_bh<0, 4>(Bb, w1p, lane, wv, acc);
    __syncthreads();                       // all S reads done

    // issue x prefetch half 0 (channels 0..63); lands during Mid-pack + P2
    float xr[16];
    #pragma unroll
    for (int j = 0; j < 16; ++j)
        xr[j] = xin[((size_t)(b * 128 + wv * 16 + j)) * 16384 + p0 + lane];

    // Mid = gelu(acc + b1), bf16-only (hi plane) -> overwrite Bb
    #pragma unroll
    for (int oi = 0; oi < 2; ++oi) {
        int o0 = wv * 32 + oi * 16 + ((lane >> 4) << 2);
        float bv[4];
        #pragma unroll
        for (int r = 0; r < 4; ++r) bv[r] = b1[o0 + r];
        #pragma unroll
        for (int pt = 0; pt < 4; ++pt) {
            int px = pt * 16 + (lane & 15);
            s4v h4;
            #pragma unroll
            for (int r = 0; r < 4; ++r) {
                __hip_bfloat16 hb = __float2bfloat16(gelu_f(acc[oi][pt][r] + bv[r]));
                h4[r] = (short)__builtin_bit_cast(unsigned short, hb);
            }
            int byt = px * 256 + ((o0 * 2) ^ ((px & 15) << 4));
            *(s4v*)(Bb + byt) = h4;
            acc[oi][pt] = (f4v){0.f, 0.f, 0.f, 0.f};
        }
    }
    __syncthreads();

    // ---- P2: acc = W2 . Mid (B hi-only, 2-term split) ----
    gemm_range_bh<0, 4>(Bb, w2p, lane, wv, acc);
    __syncthreads();                       // all Mid reads done

    // ---- P3: skip GEMM, x bf16-hi-only (2-term), two K-halves ----
    pack_write8_h(Bb, lane, wv * 16, xr);
    pack_write8_h(Bb, lane, wv * 16 + 8, xr + 8);
    #pragma unroll
    for (int j = 0; j < 16; ++j)           // half 1 (channels 64..127)
        xr[j] = xin[((size_t)(b * 128 + 64 + wv * 16 + j)) * 16384 + p0 + lane];
    __syncthreads();
    gemm_range_bh<0, 2>(Bb, wskp, lane, wv, acc);
    pack_write8_h(Bb, lane, 64 + wv * 16, xr);
    pack_write8_h(Bb, lane, 64 + wv * 16 + 8, xr + 8);
    __syncthreads();
    gemm_range_bh<2, 2>(Bb, wskp, lane, wv, acc);

    // ---- epilogue: in-place write ----
    #pragma unroll
    for (int oi = 0; oi < 2; ++oi) {
        int o0 = wv * 32 + oi * 16 + ((lane >> 4) << 2);
        float bv[4];
        #pragma unroll
        for (int r = 0; r < 4; ++r) bv[r] = b2[o0 + r] + bsk[o0 + r];
        #pragma unroll
        for (int pt = 0; pt < 4; ++pt) {
            int px = pt * 16 + (lane & 15);
            #pragma unroll
            for (int r = 0; r < 4; ++r) {
                float xv = acc[oi][pt][r] + bv[r];
                if (ACT) xv = gelu_f(xv);
                xout[((size_t)(b * 128 + o0 + r)) * 16384 + p0 + px] = xv;
            }
        }
    }
}

// ---------------- fused projection (exact 3-term path retained) ----------------
__global__ __launch_bounds__(256) void k_proj(const float* __restrict__ xin,
        const unsigned short* __restrict__ wap, const float* __restrict__ ba,
        const float* __restrict__ wb, const float* __restrict__ bb,
        float* __restrict__ outp) {
    __shared__ __align__(16) char Bb[32768];
    __shared__ float Red[256];
    int t = threadIdx.x;
    int b = blockIdx.y;
    int p0 = blockIdx.x * 64;
    int lane = t & 63, wv = t >> 6;

    float xr[16];
    #pragma unroll
    for (int j = 0; j < 16; ++j)
        xr[j] = xin[((size_t)(b * 128 + wv * 16 + j)) * 16384 + p0 + lane];
    pack_write8(Bb, lane, wv * 16, xr);
    pack_write8(Bb, lane, wv * 16 + 8, xr + 8);
    #pragma unroll
    for (int j = 0; j < 16; ++j)
        xr[j] = xin[((size_t)(b * 128 + 64 + wv * 16 + j)) * 16384 + p0 + lane];
    pack_write8(Bb, lane, 64 + wv * 16, xr);
    pack_write8(Bb, lane, 64 + wv * 16 + 8, xr + 8);
    __syncthreads();

    f4v acc[2][4];
    #pragma unroll
    for (int oi = 0; oi < 2; ++oi)
        #pragma unroll
        for (int pt = 0; pt < 4; ++pt) acc[oi][pt] = (f4v){0.f, 0.f, 0.f, 0.f};
    gemm_range<0, 4>(Bb, wap, lane, wv, acc);

    float pxsum[4] = {0.f, 0.f, 0.f, 0.f};
    #pragma unroll
    for (int oi = 0; oi < 2; ++oi) {
        int o0 = wv * 32 + oi * 16 + ((lane >> 4) << 2);
        #pragma unroll
        for (int r = 0; r < 4; ++r) {
            float bav = ba[o0 + r];
            float wbv = wb[o0 + r];
            #pragma unroll
            for (int pt = 0; pt < 4; ++pt)
                pxsum[pt] += wbv * gelu_f(acc[oi][pt][r] + bav);
        }
    }
    #pragma unroll
    for (int pt = 0; pt < 4; ++pt) {
        float v = pxsum[pt];
        v += __shfl_xor(v, 16);
        v += __shfl_xor(v, 32);
        if (lane < 16) Red[wv * 64 + pt * 16 + lane] = v;
    }
    __syncthreads();
    if (t < 64)
        outp[(size_t)b * 16384 + p0 + t] = bb[0] + Red[t] + Red[64 + t] + Red[128 + t] + Red[192 + t];
}

extern "C" void kernel_launch(void* const* d_in, const int* in_sizes, int n_in,
                              void* d_out, int out_size, void* d_ws, size_t ws_size,
                              hipStream_t stream) {
    (void)in_sizes; (void)n_in; (void)out_size;
    const float* x     = (const float*)d_in[0];
    const float* w1r   = (const float*)d_in[1];
    const float* w1i   = (const float*)d_in[2];
    const float* w2r   = (const float*)d_in[3];
    const float* w2i   = (const float*)d_in[4];
    const float* mlp1w = (const float*)d_in[5];
    const float* mlp1b = (const float*)d_in[6];
    const float* mlp2w = (const float*)d_in[7];
    const float* mlp2b = (const float*)d_in[8];
    const float* wsw   = (const float*)d_in[9];
    const float* wsb   = (const float*)d_in[10];
    const float* fc0w  = (const float*)d_in[11];
    const float* fc0b  = (const float*)d_in[12];
    const float* fc1aw = (const float*)d_in[13];
    const float* fc1ab = (const float*)d_in[14];
    const float* fc1bw = (const float*)d_in[15];
    const float* fc1bb = (const float*)d_in[16];
    float* out = (float*)d_out;

    float* ws   = (float*)d_ws;
    float* xA   = ws;                        // 33,554,432 floats
    unsigned short* Zh = (unsigned short*)(ws + 33554432);   // 8,388,608 ushort
    unsigned short* Zl = Zh + 8388608;                       // 8,388,608 ushort
    float* F    = ws + 33554432 + 4194304;   //  2,097,152 floats
    float* Ga   = F + 2097152;               //  2,097,152
    float* tabH = Ga + 2097152;              //  8192
    unsigned short* wpack = (unsigned short*)(tabH + 8192);  // 13*32768 ushort
    unsigned short* efp   = wpack + 13 * 32768;              // 8192 ushort
    unsigned short* ef2   = efp + 8192;                      // 8192 ushort
    unsigned short* ef3   = ef2 + 8192;                      // 32768 ushort
    float* Gb = (float*)(ef3 + 32768);       //  2,097,152 (tier >= 1)
    float* Gc = Gb + 2097152;                //  2,097,152 (tier 2)
    float* Gd = Gc + 2097152;                //  2,097,152 (tier 2)
    size_t need1 = ((char*)(Gb + 2097152)) - (char*)d_ws;
    size_t need2 = ((char*)(Gd + 2097152)) - (char*)d_ws;
    int tier = (ws_size >= need2) ? 2 : (ws_size >= need1) ? 1 : 0;

    k_init_tables<<<32, 256, 0, stream>>>(tabH);
    k_pack_w<<<832, 256, 0, stream>>>(mlp1w, mlp2w, wsw, fc1aw, wpack);
    k_pack_ef<<<64, 256, 0, stream>>>(efp, ef2, ef3);
    k_lift<<<32768, 256, 0, stream>>>(x, fc0w, fc0b, xA);

    for (int l = 0; l < 4; ++l) {
        k_fwd<<<2048, 256, 0, stream>>>(xA, F, efp, ef3);
        const float* l1r = w1r + (size_t)l * 4194304;
        const float* l1i = w1i + (size_t)l * 4194304;
        const float* l2r = w2r + (size_t)l * 4194304;
        const float* l2i = w2i + (size_t)l * 4194304;
        if (tier == 2) {
            k_modemix2<<<dim3(8, 32, 16), 256, 0, stream>>>(F, Ga, Gb, Gc, Gd, l1r, l1i, l2r, l2i);
            k_idft_h<4><<<2048, 256, 0, stream>>>(Ga, Gb, Gc, Gd, Zh, Zl, tabH);
        } else if (tier == 1) {
            k_modemix<1><<<dim3(8, 32, 8), 256, 0, stream>>>(F, Ga, Gb, Ga, Ga, l1r, l1i, l2r, l2i);
            k_idft_h<2><<<2048, 256, 0, stream>>>(Ga, Gb, Ga, Ga, Zh, Zl, tabH);
        } else {
            k_modemix<0><<<dim3(8, 32, 4), 256, 0, stream>>>(F, Ga, Ga, Ga, Ga, l1r, l1i, l2r, l2i);
            k_idft_h<1><<<2048, 256, 0, stream>>>(Ga, Ga, Ga, Ga, Zh, Zl, tabH);
        }
        const unsigned short* w1p  = wpack + (size_t)l * 32768;
        const unsigned short* w2p  = wpack + (size_t)(4 + l) * 32768;
        const unsigned short* wskp = wpack + (size_t)(8 + l) * 32768;
        if (l < 3)
            k_layer<1><<<dim3(256, 16), 256, 0, stream>>>(Zh, Zl, xA,
                w1p, mlp1b + l * 128, w2p, mlp2b + l * 128,
                wskp, wsb + l * 128, ef2, xA);
        else
            k_layer<0><<<dim3(256, 16), 256, 0, stream>>>(Zh, Zl, xA,
                w1p, mlp1b + l * 128, w2p, mlp2b + l * 128,
                wskp, wsb + l * 128, ef2, xA);
    }
    k_proj<<<dim3(256, 16), 256, 0, stream>>>(xA, wpack + (size_t)12 * 32768,
        fc1ab, fc1bw, fc1bb, out);
}

// Round 20
// 902.769 us; speedup vs baseline: 1.3967x; 1.3967x over previous
//
#include <hip/hip_runtime.h>
#include <hip/hip_bf16.h>
#include <math.h>

#define PI_F 3.14159265358979323846f

typedef __attribute__((ext_vector_type(8))) short s8v;
typedef __attribute__((ext_vector_type(4))) short s4v;
typedef __attribute__((ext_vector_type(4))) float f4v;

#define MFMA16(a, b, c) __builtin_amdgcn_mfma_f32_16x16x32_bf16(a, b, c, 0, 0, 0)

// fast erf, A&S 7.1.26, |err| <= ~1e-6 (rcp adds ~1ulp)
__device__ __forceinline__ float erf_f(float x) {
    float a = fabsf(x);
    float t = __builtin_amdgcn_rcpf(fmaf(0.3275911f, a, 1.0f));
    float p = t * fmaf(t, fmaf(t, fmaf(t, fmaf(t, 1.061405429f, -1.453152027f),
                1.421413741f), -0.284496736f), 0.254829592f);
    float r = 1.0f - p * __expf(-a * a);
    return copysignf(r, x);
}
__device__ __forceinline__ float gelu_f(float x) {
    return 0.5f * x * (1.0f + erf_f(x * 0.70710678118654752440f));
}

// split x = hi + lo, both bf16, via native HW converts (RNE). lo corrects hi
// exactly; total rel err ~2^-17.
__device__ __forceinline__ void split_bf16(float x, unsigned short& h, unsigned short& l) {
    __hip_bfloat16 hb = __float2bfloat16(x);
    float hf = __bfloat162float(hb);
    __hip_bfloat16 lb = __float2bfloat16(x - hf);
    h = __builtin_bit_cast(unsigned short, hb);
    l = __builtin_bit_cast(unsigned short, lb);
}

// pack 8 fp32 (consecutive k, k0 mult of 8) into swizzled hi/lo LDS B-buffer
// layout: [px 0..63][k 0..127] bf16, hi @0, lo @16384; byte ^= ((px&15)<<4)
__device__ __forceinline__ void pack_write8(char* Bb, int px, int k0, const float* v) {
    s8v hv, lv;
    #pragma unroll
    for (int j = 0; j < 8; ++j) {
        unsigned short h, l;
        split_bf16(v[j], h, l);
        hv[j] = (short)h; lv[j] = (short)l;
    }
    int byt = px * 256 + ((k0 * 2) ^ ((px & 15) << 4));
    *(s8v*)(Bb + byt) = hv;
    *(s8v*)(Bb + 16384 + byt) = lv;
}

// 128(o) x 64(px) x 32*KCN(k) GEMM accumulate via split-bf16 MFMA (3-term)
template<int KC0, int KCN>
__device__ __forceinline__ void gemm_range(const char* Bb, const unsigned short* wp,
                                           int lane, int wv, f4v acc[2][4]) {
    #pragma unroll
    for (int kc = KC0; kc < KC0 + KCN; ++kc) {
        s8v bh[4], bl[4];
        int k0 = kc * 32 + ((lane >> 4) << 3);
        #pragma unroll
        for (int pt = 0; pt < 4; ++pt) {
            int px = pt * 16 + (lane & 15);
            int byt = px * 256 + ((k0 * 2) ^ ((px & 15) << 4));
            bh[pt] = *(const s8v*)(Bb + byt);
            bl[pt] = *(const s8v*)(Bb + 16384 + byt);
        }
        #pragma unroll
        for (int oi = 0; oi < 2; ++oi) {
            const unsigned short* ap = wp + (wv * 2 + oi) * 2048 + kc * 512 + lane * 8;
            s8v ah = *(const s8v*)ap;
            s8v al = *(const s8v*)(ap + 16384);
            #pragma unroll
            for (int pt = 0; pt < 4; ++pt) {
                acc[oi][pt] = MFMA16(ah, bh[pt], acc[oi][pt]);
                acc[oi][pt] = MFMA16(ah, bl[pt], acc[oi][pt]);
                acc[oi][pt] = MFMA16(al, bh[pt], acc[oi][pt]);
            }
        }
    }
}

// B-hi-only variant (2-term): B rounded to bf16, A full split. Used for S/Mid GEMMs.
template<int KC0, int KCN>
__device__ __forceinline__ void gemm_range_bh(const char* Bb, const unsigned short* wp,
                                              int lane, int wv, f4v acc[2][4]) {
    #pragma unroll
    for (int kc = KC0; kc < KC0 + KCN; ++kc) {
        s8v bh[4];
        int k0 = kc * 32 + ((lane >> 4) << 3);
        #pragma unroll
        for (int pt = 0; pt < 4; ++pt) {
            int px = pt * 16 + (lane & 15);
            int byt = px * 256 + ((k0 * 2) ^ ((px & 15) << 4));
            bh[pt] = *(const s8v*)(Bb + byt);
        }
        #pragma unroll
        for (int oi = 0; oi < 2; ++oi) {
            const unsigned short* ap = wp + (wv * 2 + oi) * 2048 + kc * 512 + lane * 8;
            s8v ah = *(const s8v*)ap;
            s8v al = *(const s8v*)(ap + 16384);
            #pragma unroll
            for (int pt = 0; pt < 4; ++pt) {
                acc[oi][pt] = MFMA16(ah, bh[pt], acc[oi][pt]);
                acc[oi][pt] = MFMA16(al, bh[pt], acc[oi][pt]);
            }
        }
    }
}

// ---------------- weight pre-split+pack: 13 fp32 128x128 mats ----------------
__global__ __launch_bounds__(256) void k_pack_w(const float* __restrict__ mlp1w,
        const float* __restrict__ mlp2w, const float* __restrict__ wsw,
        const float* __restrict__ fc1aw, unsigned short* __restrict__ wpack) {
    int idx = blockIdx.x * 256 + threadIdx.x;
    if (idx >= 212992) return;           // 13 * 16384
    int mat = idx >> 14, e = idx & 16383;
    const float* src = mat < 4  ? mlp1w + mat * 16384 + e
                     : mat < 8  ? mlp2w + (mat - 4) * 16384 + e
                     : mat < 12 ? wsw + (mat - 8) * 16384 + e
                                : fc1aw + e;
    float x = *src;
    unsigned short h, l;
    split_bf16(x, h, l);
    int o = e >> 7, i = e & 127;
    int pos = (o >> 4) * 2048 + (i >> 5) * 512 + (((i >> 3) & 3) * 16 + (o & 15)) * 8 + (i & 7);
    wpack[(size_t)mat * 32768 + pos] = h;
    wpack[(size_t)mat * 32768 + 16384 + pos] = l;
}

// ---------------- twiddle fragment tables ----------------
__global__ void k_pack_ef(unsigned short* __restrict__ efp,
                          unsigned short* __restrict__ ef2,
                          unsigned short* __restrict__ ef3) {
    int t = blockIdx.x * 256 + threadIdx.x;
    if (t < 4096) {
        int j = t & 7, lane = (t >> 3) & 63, nt = (t >> 9) & 1, kc = t >> 10;
        int w = kc * 32 + ((lane >> 4) << 3) + j;
        int q = nt * 16 + (lane & 15);
        int ky = q >> 1, c = q & 1;
        int m = (ky * w) & 127;
        float th = (2.0f * PI_F / 128.0f) * (float)m;
        float v = c ? -sinf(th) : cosf(th);
        unsigned short h, l;
        split_bf16(v, h, l);
        efp[t] = h;
        efp[4096 + t] = l;
    }
    if (t < 4096) {
        int j = t & 7, lane = (t >> 3) & 63, wt = t >> 9;
        int w = wt * 16 + (lane & 15);
        int q = ((lane >> 4) << 3) + j;
        int ky = q >> 1, c = q & 1;
        float g = (ky == 0 ? 1.0f : 2.0f) * (1.0f / 16384.0f);
        int m = (ky * w) & 127;
        float th = (2.0f * PI_F / 128.0f) * (float)m;
        float v = (c ? -sinf(th) : cosf(th)) * g;
        unsigned short h, l;
        split_bf16(v, h, l);
        ef2[t] = h;
        ef2[4096 + t] = l;
    }
    if (t < 16384) {
        int j = t & 7, lane = (t >> 3) & 63, kt = (t >> 9) & 7, ct = t >> 12;
        int k = kt * 32 + ((lane >> 4) << 3) + j;
        int col = ct * 16 + (lane & 15);
        int h = k >> 1, cb = k & 1;
        int kxi = col >> 1, cp = col & 1;
        int f = kxi < 16 ? kxi : kxi - 32;
        int m = ((f * h) % 128 + 128) & 127;
        float th = (2.0f * PI_F / 128.0f) * (float)m;
        float Er = cosf(th), Ei = -sinf(th);
        float v = (cb == 0) ? (cp == 0 ? Er : Ei) : (cp == 0 ? -Ei : Er);
        unsigned short hh, ll;
        split_bf16(v, hh, ll);
        ef3[t] = hh;
        ef3[16384 + t] = ll;
    }
}

// ---------------- tabH for inverse h-DFT ----------------
__global__ void k_init_tables(float* __restrict__ tabH) {
    int idx = blockIdx.x * 256 + threadIdx.x;
    if (idx < 8192) {
        int c = idx & 1, kxi = (idx >> 1) & 31, h = idx >> 6;
        int f = kxi < 16 ? kxi : kxi - 32;
        int m = ((f * h) % 128 + 128) & 127;
        float th = (2.0f * PI_F / 128.0f) * (float)m;
        tabH[idx] = c ? -sinf(th) : cosf(th);
    }
}

// ---------------- lifting (4 px / thread, float4) ----------------
__global__ __launch_bounds__(256) void k_lift(const float* __restrict__ xin,
        const float* __restrict__ w0, const float* __restrict__ b0,
        float* __restrict__ xout) {
    int idx = blockIdx.x * 256 + threadIdx.x;     // 8,388,608 quads
    int wq = idx & 31, h = (idx >> 5) & 127, c = (idx >> 12) & 127, b = idx >> 19;
    const float4* xp = (const float4*)(xin + ((size_t)(b * 128 + h) * 128 + wq * 4) * 2);
    float4 p01 = xp[0], p23 = xp[1];
    float wa = w0[c], wbv = w0[128 + c], wg = w0[256 + c], wd = w0[384 + c];
    float base = (float)h * (1.0f / 127.0f) * wg + b0[c];
    float ws = (1.0f / 127.0f) * wd;
    float4 v;
    v.x = p01.x * wa + p01.y * wbv + (float)(wq * 4 + 0) * ws + base;
    v.y = p01.z * wa + p01.w * wbv + (float)(wq * 4 + 1) * ws + base;
    v.z = p23.x * wa + p23.y * wbv + (float)(wq * 4 + 2) * ws + base;
    v.w = p23.z * wa + p23.w * wbv + (float)(wq * 4 + 3) * ws + base;
    *(float4*)(xout + ((size_t)(b * 128 + c) * 128 + h) * 128 + wq * 4) = v;
}

// ---------------- fused forward transform: x(b,c) -> F[bi][kxi*16+ky]cplx ------
__global__ __launch_bounds__(256) void k_fwd(const float* __restrict__ x,
        float* __restrict__ F, const unsigned short* __restrict__ efp,
        const unsigned short* __restrict__ ef3) {
    __shared__ __align__(16) char Xb[32768];
    __shared__ __align__(16) char Tq[16384];
    int t = threadIdx.x;
    int bi = blockIdx.x;
    int lane = t & 63, wv = t >> 6;
    const float4* xg = (const float4*)(x + (size_t)bi * 16384);

    for (int half = 0; half < 2; ++half) {
        __syncthreads();
        #pragma unroll
        for (int k = 0; k < 8; ++k) {
            int idx4 = k * 256 + t;
            float4 f = xg[half * 2048 + idx4];
            int row = idx4 >> 5;
            int w0 = (idx4 & 31) * 4;
            s4v h4, l4;
            const float* fp = (const float*)&f;
            #pragma unroll
            for (int q = 0; q < 4; ++q) {
                unsigned short hh, ll;
                split_bf16(fp[q], hh, ll);
                h4[q] = (short)hh; l4[q] = (short)ll;
            }
            int byt = row * 256 + ((w0 * 2) ^ ((row & 15) << 4));
            *(s4v*)(Xb + byt) = h4;
            *(s4v*)(Xb + 16384 + byt) = l4;
        }
        __syncthreads();
        f4v acc[2];
        acc[0] = (f4v){0.f, 0.f, 0.f, 0.f};
        acc[1] = (f4v){0.f, 0.f, 0.f, 0.f};
        #pragma unroll
        for (int kc = 0; kc < 4; ++kc) {
            int row = wv * 16 + (lane & 15);
            int k0 = kc * 32 + ((lane >> 4) << 3);
            int byt = row * 256 + ((k0 * 2) ^ ((row & 15) << 4));
            s8v ah = *(const s8v*)(Xb + byt);
            s8v al = *(const s8v*)(Xb + 16384 + byt);
            #pragma unroll
            for (int nt = 0; nt < 2; ++nt) {
                const unsigned short* bp = efp + ((kc * 2 + nt) * 64 + lane) * 8;
                s8v bh = *(const s8v*)bp;
                s8v bl = *(const s8v*)(bp + 4096);
                acc[nt] = MFMA16(ah, bh, acc[nt]);
                acc[nt] = MFMA16(ah, bl, acc[nt]);
                acc[nt] = MFMA16(al, bh, acc[nt]);
            }
        }
        // scatter T (split-bf16) into Tq: T[h][q] -> Tq[ky=q>>1][k=2h+(q&1)]
        #pragma unroll
        for (int nt = 0; nt < 2; ++nt) {
            int q = nt * 16 + (lane & 15);
            int ky = q >> 1, c = q & 1;
            #pragma unroll
            for (int r = 0; r < 4; ++r) {
                int h = half * 64 + wv * 16 + ((lane >> 4) << 2) + r;
                unsigned short hh, ll;
                split_bf16(acc[nt][r], hh, ll);
                int byt = ky * 512 + ((4 * h + 2 * c) ^ ((ky & 15) << 4));
                *(unsigned short*)(Tq + byt) = hh;
                *(unsigned short*)(Tq + 8192 + byt) = ll;
            }
        }
    }
    __syncthreads();
    f4v fa = (f4v){0.f, 0.f, 0.f, 0.f};
    #pragma unroll
    for (int kt = 0; kt < 8; ++kt) {
        int ky = lane & 15;
        int byt = ky * 512 + ((kt * 64 + ((lane >> 4) << 4)) ^ ((ky & 15) << 4));
        s8v ah = *(const s8v*)(Tq + byt);
        s8v al = *(const s8v*)(Tq + 8192 + byt);
        const unsigned short* bp = ef3 + ((wv * 8 + kt) * 64 + lane) * 8;
        s8v bh = *(const s8v*)bp;
        s8v bl = *(const s8v*)(bp + 16384);
        fa = MFMA16(ah, bh, fa);
        fa = MFMA16(ah, bl, fa);
        fa = MFMA16(al, bh, fa);
    }
    int col = wv * 16 + (lane & 15);
    int kxi = col >> 1, cp = col & 1;
    float* Fb = F + (size_t)bi * 1024 + kxi * 32 + cp;
    #pragma unroll
    for (int r = 0; r < 4; ++r) {
        int ky = ((lane >> 4) << 2) + r;
        Fb[ky * 2] = fa[r];
    }
}

// ---------------- modemix v3 (tier 2): F staged through LDS (32KB), 2 stages ----
// LDS 32KB -> 4 blocks/CU is the hard cap (160KB/CU); (256,4) matches it.
__global__ __launch_bounds__(256, 4) void k_modemix2(const float* __restrict__ F,
        float* __restrict__ G0, float* __restrict__ G1,
        float* __restrict__ G2, float* __restrict__ G3,
        const float* __restrict__ w1r, const float* __restrict__ w1i,
        const float* __restrict__ w2r, const float* __restrict__ w2i) {
    __shared__ __align__(16) float2 Fs[4096];    // [b 4][i 16][m 64], 32 KB
    int t = threadIdx.x;
    int m = blockIdx.x * 64 + (t & 63);
    int o = blockIdx.y * 4 + (t >> 6);
    int bz = blockIdx.z;
    int iq = bz >> 2;
    int bq = bz & 3;
    const size_t i0 = (size_t)iq * 32;
    int b0 = bq * 4;
    const float* wrp = (m < 256) ? w1r : w2r;
    const float* wip = (m < 256) ? w1i : w2i;
    int ms = m & 255;
    float accr[4], acci[4];
    #pragma unroll
    for (int b = 0; b < 4; ++b) { accr[b] = 0.f; acci[b] = 0.f; }
    const float* wrb = wrp + (i0 * 128 + o) * 256 + ms;
    const float* wib = wip + (i0 * 128 + o) * 256 + ms;
    int m0 = blockIdx.x * 64;
    const float2* F2 = (const float2*)F;

    for (int ih = 0; ih < 2; ++ih) {
        __syncthreads();                         // protect Fs reuse
        #pragma unroll
        for (int k = 0; k < 16; ++k) {
            int idx = k * 256 + t;               // m=idx&63, i=(idx>>6)&15, b=idx>>10
            int fm = idx & 63, fi = (idx >> 6) & 15, fb = idx >> 10;
            Fs[idx] = F2[(size_t)(b0 + fb) * 65536 + (i0 + ih * 16 + fi) * 512 + m0 + fm];
        }
        __syncthreads();
        int ml = t & 63;
        #pragma unroll 4
        for (int ii = 0; ii < 16; ++ii) {
            size_t gi = (size_t)(ih * 16 + ii);
            float wr = wrb[gi * 32768];
            float wi = wib[gi * 32768];
            const float2* fp = Fs + ii * 64 + ml;
            #pragma unroll
            for (int b = 0; b < 4; ++b) {
                float2 f = fp[b * 1024];
                accr[b] += f.x * wr - f.y * wi;
                acci[b] += f.x * wi + f.y * wr;
            }
        }
    }
    float* Gsel = (iq == 0 ? G0 : iq == 1 ? G1 : iq == 2 ? G2 : G3);
    float2* Gp = (float2*)Gsel;
    #pragma unroll
    for (int b = 0; b < 4; ++b) {
        Gp[(size_t)(b0 + b) * 65536 + (size_t)o * 512 + m] = make_float2(accr[b], acci[b]);
    }
}

// ---------------- per-mode complex C x C mix, fallback tiers (0/1) ----------------
template<int TIER>
__global__ __launch_bounds__(256, 4) void k_modemix(const float* __restrict__ F,
        float* __restrict__ G0, float* __restrict__ G1,
        float* __restrict__ G2, float* __restrict__ G3,
        const float* __restrict__ w1r, const float* __restrict__ w1i,
        const float* __restrict__ w2r, const float* __restrict__ w2i) {
    int t = threadIdx.x;
    int m = blockIdx.x * 64 + (t & 63);
    int o = blockIdx.y * 4 + (t >> 6);
    int bz = blockIdx.z;
    int iq = (TIER == 0) ? 0 : (bz >> 2);
    int bq = (TIER == 0) ? bz : (bz & 3);
    const int ni = (TIER == 1) ? 64 : 128;
    const size_t i0 = (size_t)iq * ni;
    int b0 = bq * 4;
    const float* wrp = (m < 256) ? w1r : w2r;
    const float* wip = (m < 256) ? w1i : w2i;
    int ms = m & 255;
    float accr[4], acci[4];
    #pragma unroll
    for (int b = 0; b < 4; ++b) { accr[b] = 0.f; acci[b] = 0.f; }
    const float* wrb = wrp + (i0 * 128 + o) * 256 + ms;
    const float* wib = wip + (i0 * 128 + o) * 256 + ms;
    const float2* F2 = (const float2*)F + (size_t)b0 * 65536 + i0 * 512 + m;
    #pragma unroll 4
    for (int ii = 0; ii < ni; ++ii) {
        float wr = wrb[(size_t)ii * 32768];
        float wi = wib[(size_t)ii * 32768];
        const float2* Fp = F2 + (size_t)ii * 512;
        #pragma unroll
        for (int b = 0; b < 4; ++b) {
            float2 f = Fp[(size_t)b * 65536];
            accr[b] += f.x * wr - f.y * wi;
            acci[b] += f.x * wi + f.y * wr;
        }
    }
    float* Gsel = (TIER == 1) ? (iq ? G1 : G0) : G0;
    float2* Gp = (float2*)Gsel;
    #pragma unroll
    for (int b = 0; b < 4; ++b) {
        Gp[(size_t)(b0 + b) * 65536 + (size_t)o * 512 + m] = make_float2(accr[b], acci[b]);
    }
}

// ---------------- inverse DFT along h -> Z (bf16 hi/lo, h-major [b][h][c][q]) ----
template<int NADD>
__global__ __launch_bounds__(256) void k_idft_h(const float* __restrict__ G0,
        const float* __restrict__ G1, const float* __restrict__ G2,
        const float* __restrict__ G3, unsigned short* __restrict__ Zh,
        unsigned short* __restrict__ Zl, const float* __restrict__ tabH) {
    __shared__ float Gs[1024];
    __shared__ float Eh[8192];
    int t = threadIdx.x, bo = blockIdx.x;
    #pragma unroll
    for (int k = 0; k < 32; ++k) Eh[k * 256 + t] = tabH[k * 256 + t];
    size_t base = (size_t)bo * 1024;
    #pragma unroll
    for (int k = 0; k < 4; ++k) {
        size_t off = base + k * 256 + t;
        float v = G0[off];
        if (NADD > 1) v += G1[off];
        if (NADD > 2) { v += G2[off]; v += G3[off]; }
        Gs[k * 256 + t] = v;
    }
    __syncthreads();
    int ky = t & 15, hb = t >> 4;
    float zr[8], zi[8];
    #pragma unroll
    for (int j = 0; j < 8; ++j) { zr[j] = 0.f; zi[j] = 0.f; }
    for (int kxi = 0; kxi < 32; ++kxi) {
        float gr = Gs[(kxi * 16 + ky) * 2], gi = Gs[(kxi * 16 + ky) * 2 + 1];
        #pragma unroll
        for (int j = 0; j < 8; ++j) {
            int h = hb + 16 * j;
            float c = Eh[h * 64 + kxi * 2], s = Eh[h * 64 + kxi * 2 + 1];
            zr[j] += gr * c + gi * s;
            zi[j] += gi * c - gr * s;
        }
    }
    int b = bo >> 7, c = bo & 127;
    #pragma unroll
    for (int j = 0; j < 8; ++j) {
        int h = hb + 16 * j;
        size_t off = (((size_t)(b * 128 + h)) * 128 + c) * 32 + ky * 2;
        unsigned short hh, ll;
        split_bf16(zr[j], hh, ll);
        Zh[off] = hh; Zl[off] = ll;
        split_bf16(zi[j], hh, ll);
        Zh[off + 1] = hh; Zl[off + 1] = ll;
    }
}

// ---------------- fused layer tail: Z(split,h-major) -> S (MFMA idft_w) -> MLP + skip ----
template<int ACT>
__global__ __launch_bounds__(256, 4) void k_layer(
    const unsigned short* __restrict__ Zh, const unsigned short* __restrict__ Zl,
    const float* __restrict__ xin,
    const unsigned short* __restrict__ w1p, const float* __restrict__ b1,
    const unsigned short* __restrict__ w2p, const float* __restrict__ b2,
    const unsigned short* __restrict__ wskp, const float* __restrict__ bsk,
    const unsigned short* __restrict__ ef2, float* __restrict__ xout)
{
    __shared__ __align__(16) char Bb[32768];
    int t = threadIdx.x;
    int b = blockIdx.y;
    int p0 = blockIdx.x * 64;
    int h = p0 >> 7, w0 = p0 & 127;
    int lane = t & 63, wv = t >> 6;

    // ---- P0: S = Z . E2 via MFMA (K=32); Z coalesced; S stored bf16-HI-ONLY ----
    {
        int q0 = (lane >> 4) << 3;
        s8v zah[2], zal[2];
        #pragma unroll
        for (int ct = 0; ct < 2; ++ct) {
            int c = wv * 32 + ct * 16 + (lane & 15);
            size_t off = (((size_t)(b * 128 + h)) * 128 + c) * 32 + q0;
            zah[ct] = *(const s8v*)(Zh + off);
            zal[ct] = *(const s8v*)(Zl + off);
        }
        int wtg0 = w0 >> 4;
        #pragma unroll
        for (int wt = 0; wt < 4; ++wt) {
            const unsigned short* bp = ef2 + ((wtg0 + wt) * 64 + lane) * 8;
            s8v bh = *(const s8v*)bp;
            s8v bl = *(const s8v*)(bp + 4096);
            #pragma unroll
            for (int ct = 0; ct < 2; ++ct) {
                f4v c4 = (f4v){0.f, 0.f, 0.f, 0.f};
                c4 = MFMA16(zah[ct], bh, c4);
                c4 = MFMA16(zah[ct], bl, c4);
                c4 = MFMA16(zal[ct], bh, c4);
                int px = wt * 16 + (lane & 15);
                int c0 = wv * 32 + ct * 16 + ((lane >> 4) << 2);
                s4v h4;
                #pragma unroll
                for (int r = 0; r < 4; ++r) {
                    __hip_bfloat16 hb = __float2bfloat16(c4[r]);
                    h4[r] = (short)__builtin_bit_cast(unsigned short, hb);
                }
                int byt = px * 256 + ((c0 * 2) ^ ((px & 15) << 4));
                *(s4v*)(Bb + byt) = h4;
            }
        }
    }
    __syncthreads();

    f4v acc[2][4];
    #pragma unroll
    for (int oi = 0; oi < 2; ++oi)
        #pragma unroll
        for (int pt = 0; pt < 4; ++pt) acc[oi][pt] = (f4v){0.f, 0.f, 0.f, 0.f};

    // ---- P1: acc = W1 . S (B hi-only, 2-term) ----
    gemm_range_bh<0, 4>(Bb, w1p, lane, wv, acc);
    __syncthreads();                       // all S reads done

    // issue x prefetch half 0 (channels 0..63); lands during Mid-pack + P2
    float xr[16];
    #pragma unroll
    for (int j = 0; j < 16; ++j)
        xr[j] = xin[((size_t)(b * 128 + wv * 16 + j)) * 16384 + p0 + lane];

    // Mid = gelu(acc + b1), bf16-only (hi plane) -> overwrite Bb
    #pragma unroll
    for (int oi = 0; oi < 2; ++oi) {
        int o0 = wv * 32 + oi * 16 + ((lane >> 4) << 2);
        float bv[4];
        #pragma unroll
        for (int r = 0; r < 4; ++r) bv[r] = b1[o0 + r];
        #pragma unroll
        for (int pt = 0; pt < 4; ++pt) {
            int px = pt * 16 + (lane & 15);
            s4v h4;
            #pragma unroll
            for (int r = 0; r < 4; ++r) {
                __hip_bfloat16 hb = __float2bfloat16(gelu_f(acc[oi][pt][r] + bv[r]));
                h4[r] = (short)__builtin_bit_cast(unsigned short, hb);
            }
            int byt = px * 256 + ((o0 * 2) ^ ((px & 15) << 4));
            *(s4v*)(Bb + byt) = h4;
            acc[oi][pt] = (f4v){0.f, 0.f, 0.f, 0.f};
        }
    }
    __syncthreads();

    // ---- P2: acc = W2 . Mid (B hi-only, 2-term split) ----
    gemm_range_bh<0, 4>(Bb, w2p, lane, wv, acc);
    __syncthreads();                       // all Mid reads done

    // ---- P3: skip GEMM in two K-halves (full 3-term split for accuracy) ----
    pack_write8(Bb, lane, wv * 16, xr);
    pack_write8(Bb, lane, wv * 16 + 8, xr + 8);
    #pragma unroll
    for (int j = 0; j < 16; ++j)           // half 1 (channels 64..127)
        xr[j] = xin[((size_t)(b * 128 + 64 + wv * 16 + j)) * 16384 + p0 + lane];
    __syncthreads();
    gemm_range<0, 2>(Bb, wskp, lane, wv, acc);
    pack_write8(Bb, lane, 64 + wv * 16, xr);
    pack_write8(Bb, lane, 64 + wv * 16 + 8, xr + 8);
    __syncthreads();
    gemm_range<2, 2>(Bb, wskp, lane, wv, acc);

    // ---- epilogue: in-place write ----
    #pragma unroll
    for (int oi = 0; oi < 2; ++oi) {
        int o0 = wv * 32 + oi * 16 + ((lane >> 4) << 2);
        float bv[4];
        #pragma unroll
        for (int r = 0; r < 4; ++r) bv[r] = b2[o0 + r] + bsk[o0 + r];
        #pragma unroll
        for (int pt = 0; pt < 4; ++pt) {
            int px = pt * 16 + (lane & 15);
            #pragma unroll
            for (int r = 0; r < 4; ++r) {
                float xv = acc[oi][pt][r] + bv[r];
                if (ACT) xv = gelu_f(xv);
                xout[((size_t)(b * 128 + o0 + r)) * 16384 + p0 + px] = xv;
            }
        }
    }
}

// ---------------- fused projection ----------------
__global__ __launch_bounds__(256) void k_proj(const float* __restrict__ xin,
        const unsigned short* __restrict__ wap, const float* __restrict__ ba,
        const float* __restrict__ wb, const float* __restrict__ bb,
        float* __restrict__ outp) {
    __shared__ __align__(16) char Bb[32768];
    __shared__ float Red[256];
    int t = threadIdx.x;
    int b = blockIdx.y;
    int p0 = blockIdx.x * 64;
    int lane = t & 63, wv = t >> 6;

    float xr[16];
    #pragma unroll
    for (int j = 0; j < 16; ++j)
        xr[j] = xin[((size_t)(b * 128 + wv * 16 + j)) * 16384 + p0 + lane];
    pack_write8(Bb, lane, wv * 16, xr);
    pack_write8(Bb, lane, wv * 16 + 8, xr + 8);
    #pragma unroll
    for (int j = 0; j < 16; ++j)
        xr[j] = xin[((size_t)(b * 128 + 64 + wv * 16 + j)) * 16384 + p0 + lane];
    pack_write8(Bb, lane, 64 + wv * 16, xr);
    pack_write8(Bb, lane, 64 + wv * 16 + 8, xr + 8);
    __syncthreads();

    f4v acc[2][4];
    #pragma unroll
    for (int oi = 0; oi < 2; ++oi)
        #pragma unroll
        for (int pt = 0; pt < 4; ++pt) acc[oi][pt] = (f4v){0.f, 0.f, 0.f, 0.f};
    gemm_range<0, 4>(Bb, wap, lane, wv, acc);

    float pxsum[4] = {0.f, 0.f, 0.f, 0.f};
    #pragma unroll
    for (int oi = 0; oi < 2; ++oi) {
        int o0 = wv * 32 + oi * 16 + ((lane >> 4) << 2);
        #pragma unroll
        for (int r = 0; r < 4; ++r) {
            float bav = ba[o0 + r];
            float wbv = wb[o0 + r];
            #pragma unroll
            for (int pt = 0; pt < 4; ++pt)
                pxsum[pt] += wbv * gelu_f(acc[oi][pt][r] + bav);
        }
    }
    #pragma unroll
    for (int pt = 0; pt < 4; ++pt) {
        float v = pxsum[pt];
        v += __shfl_xor(v, 16);
        v += __shfl_xor(v, 32);
        if (lane < 16) Red[wv * 64 + pt * 16 + lane] = v;
    }
    __syncthreads();
    if (t < 64)
        outp[(size_t)b * 16384 + p0 + t] = bb[0] + Red[t] + Red[64 + t] + Red[128 + t] + Red[192 + t];
}

extern "C" void kernel_launch(void* const* d_in, const int* in_sizes, int n_in,
                              void* d_out, int out_size, void* d_ws, size_t ws_size,
                              hipStream_t stream) {
    (void)in_sizes; (void)n_in; (void)out_size;
    const float* x     = (const float*)d_in[0];
    const float* w1r   = (const float*)d_in[1];
    const float* w1i   = (const float*)d_in[2];
    const float* w2r   = (const float*)d_in[3];
    const float* w2i   = (const float*)d_in[4];
    const float* mlp1w = (const float*)d_in[5];
    const float* mlp1b = (const float*)d_in[6];
    const float* mlp2w = (const float*)d_in[7];
    const float* mlp2b = (const float*)d_in[8];
    const float* wsw   = (const float*)d_in[9];
    const float* wsb   = (const float*)d_in[10];
    const float* fc0w  = (const float*)d_in[11];
    const float* fc0b  = (const float*)d_in[12];
    const float* fc1aw = (const float*)d_in[13];
    const float* fc1ab = (const float*)d_in[14];
    const float* fc1bw = (const float*)d_in[15];
    const float* fc1bb = (const float*)d_in[16];
    float* out = (float*)d_out;

    float* ws   = (float*)d_ws;
    float* xA   = ws;                        // 33,554,432 floats
    unsigned short* Zh = (unsigned short*)(ws + 33554432);   // 8,388,608 ushort
    unsigned short* Zl = Zh + 8388608;                       // 8,388,608 ushort
    float* F    = ws + 33554432 + 4194304;   //  2,097,152 floats
    float* Ga   = F + 2097152;               //  2,097,152
    float* tabH = Ga + 2097152;              //  8192
    unsigned short* wpack = (unsigned short*)(tabH + 8192);  // 13*32768 ushort
    unsigned short* efp   = wpack + 13 * 32768;              // 8192 ushort
    unsigned short* ef2   = efp + 8192;                      // 8192 ushort
    unsigned short* ef3   = ef2 + 8192;                      // 32768 ushort
    float* Gb = (float*)(ef3 + 32768);       //  2,097,152 (tier >= 1)
    float* Gc = Gb + 2097152;                //  2,097,152 (tier 2)
    float* Gd = Gc + 2097152;                //  2,097,152 (tier 2)
    size_t need1 = ((char*)(Gb + 2097152)) - (char*)d_ws;
    size_t need2 = ((char*)(Gd + 2097152)) - (char*)d_ws;
    int tier = (ws_size >= need2) ? 2 : (ws_size >= need1) ? 1 : 0;

    k_init_tables<<<32, 256, 0, stream>>>(tabH);
    k_pack_w<<<832, 256, 0, stream>>>(mlp1w, mlp2w, wsw, fc1aw, wpack);
    k_pack_ef<<<64, 256, 0, stream>>>(efp, ef2, ef3);
    k_lift<<<32768, 256, 0, stream>>>(x, fc0w, fc0b, xA);

    for (int l = 0; l < 4; ++l) {
        k_fwd<<<2048, 256, 0, stream>>>(xA, F, efp, ef3);
        const float* l1r = w1r + (size_t)l * 4194304;
        const float* l1i = w1i + (size_t)l * 4194304;
        const float* l2r = w2r + (size_t)l * 4194304;
        const float* l2i = w2i + (size_t)l * 4194304;
        if (tier == 2) {
            k_modemix2<<<dim3(8, 32, 16), 256, 0, stream>>>(F, Ga, Gb, Gc, Gd, l1r, l1i, l2r, l2i);
            k_idft_h<4><<<2048, 256, 0, stream>>>(Ga, Gb, Gc, Gd, Zh, Zl, tabH);
        } else if (tier == 1) {
            k_modemix<1><<<dim3(8, 32, 8), 256, 0, stream>>>(F, Ga, Gb, Ga, Ga, l1r, l1i, l2r, l2i);
            k_idft_h<2><<<2048, 256, 0, stream>>>(Ga, Gb, Ga, Ga, Zh, Zl, tabH);
        } else {
            k_modemix<0><<<dim3(8, 32, 4), 256, 0, stream>>>(F, Ga, Ga, Ga, Ga, l1r, l1i, l2r, l2i);
            k_idft_h<1><<<2048, 256, 0, stream>>>(Ga, Ga, Ga, Ga, Zh, Zl, tabH);
        }
        const unsigned short* w1p  = wpack + (size_t)l * 32768;
        const unsigned short* w2p  = wpack + (size_t)(4 + l) * 32768;
        const unsigned short* wskp = wpack + (size_t)(8 + l) * 32768;
        if (l < 3)
            k_layer<1><<<dim3(256, 16), 256, 0, stream>>>(Zh, Zl, xA,
                w1p, mlp1b + l * 128, w2p, mlp2b + l * 128,
                wskp, wsb + l * 128, ef2, xA);
        else
            k_layer<0><<<dim3(256, 16), 256, 0, stream>>>(Zh, Zl, xA,
                w1p, mlp1b + l * 128, w2p, mlp2b + l * 128,
                wskp, wsb + l * 128, ef2, xA);
    }
    k_proj<<<dim3(256, 16), 256, 0, stream>>>(xA, wpack + (size_t)12 * 32768,
        fc1ab, fc1bw, fc1bb, out);
}